// Round 11
// baseline (6499.321 us; speedup 1.0000x reference)
//
#include <hip/hip_runtime.h>

#define TT 1024
#define BB 64
#define FF 256
#define HH 512

// ---------------------------------------------------------------------------
// Kernel 1: i_n = x @ W_ih^T + b_ih  -> io (= d_out).  (unchanged)
// ---------------------------------------------------------------------------
__global__ __launch_bounds__(256) void in_gemm(
    const float* __restrict__ x, const float* __restrict__ Wih,
    const float* __restrict__ bih, float* __restrict__ io)
{
    __shared__ float xs[32][68];
    __shared__ float wst[64][68];

    const int bid = blockIdx.x;
    const int rb = bid >> 3, cb = bid & 7;
    const int m0 = rb * 32, n0 = cb * 64;
    const int t  = threadIdx.x;
    const int ti = t >> 4, tj = t & 15;

    float acc[2][4] = {{0.f,0.f,0.f,0.f},{0.f,0.f,0.f,0.f}};

    for (int k0 = 0; k0 < FF; k0 += 64) {
        {
            int flat = t * 8;
            int row = flat >> 6, col = flat & 63;
            const float* src = &x[(size_t)(m0 + row) * FF + k0 + col];
            float4 a = *(const float4*)&src[0];
            float4 b = *(const float4*)&src[4];
            *(float4*)&xs[row][col]     = a;
            *(float4*)&xs[row][col + 4] = b;
        }
        {
            int j  = t >> 2;
            int kk = (t & 3) * 16;
            const float* src = &Wih[(size_t)(n0 + j) * FF + k0 + kk];
            #pragma unroll
            for (int q = 0; q < 4; ++q) {
                float4 v = *(const float4*)&src[q * 4];
                wst[kk + q*4 + 0][j] = v.x;
                wst[kk + q*4 + 1][j] = v.y;
                wst[kk + q*4 + 2][j] = v.z;
                wst[kk + q*4 + 3][j] = v.w;
            }
        }
        __syncthreads();
        #pragma unroll
        for (int k = 0; k < 64; k += 4) {
            float4 xa = *(const float4*)&xs[ti][k];
            float4 xb = *(const float4*)&xs[ti + 16][k];
            #pragma unroll
            for (int q = 0; q < 4; ++q) {
                float4 wv = *(const float4*)&wst[k + q][tj * 4];
                float xav = (&xa.x)[q], xbv = (&xb.x)[q];
                acc[0][0] = fmaf(xav, wv.x, acc[0][0]);
                acc[0][1] = fmaf(xav, wv.y, acc[0][1]);
                acc[0][2] = fmaf(xav, wv.z, acc[0][2]);
                acc[0][3] = fmaf(xav, wv.w, acc[0][3]);
                acc[1][0] = fmaf(xbv, wv.x, acc[1][0]);
                acc[1][1] = fmaf(xbv, wv.y, acc[1][1]);
                acc[1][2] = fmaf(xbv, wv.z, acc[1][2]);
                acc[1][3] = fmaf(xbv, wv.w, acc[1][3]);
            }
        }
        __syncthreads();
    }

    float4 bv = *(const float4*)&bih[n0 + tj * 4];
    float4 r0 = make_float4(acc[0][0]+bv.x, acc[0][1]+bv.y, acc[0][2]+bv.z, acc[0][3]+bv.w);
    float4 r1 = make_float4(acc[1][0]+bv.x, acc[1][1]+bv.y, acc[1][2]+bv.z, acc[1][3]+bv.w);
    *(float4*)&io[(size_t)(m0 + ti)      * HH + n0 + tj * 4] = r0;
    *(float4*)&io[(size_t)(m0 + ti + 16) * HH + n0 + tj * 4] = r1;
}

// ---------------------------------------------------------------------------
// Kernel 2: the REAL recurrence — r9 verbatim (best: 1890 us). Untouched so
// this round's output stays correct and its timing is the stability anchor.
// ---------------------------------------------------------------------------
#define P8(A,i) "+v"(A[(i)+0]), "+v"(A[(i)+1]), "+v"(A[(i)+2]), "+v"(A[(i)+3]), \
                "+v"(A[(i)+4]), "+v"(A[(i)+5]), "+v"(A[(i)+6]), "+v"(A[(i)+7])

__global__ __launch_bounds__(512, 2) void mgu_rec(
    const float* __restrict__ Whh, const float* __restrict__ bhh,
    float* __restrict__ io, float* __restrict__ hbuf)
{
    const int bid = blockIdx.x;
    const int s   = bid >> 5;
    const int g   = bid & 31;
    const int c0  = g * 2;
    const int tid = threadIdx.x;
    const int w   = tid >> 6;
    const int l   = tid & 63;

    __shared__ float hst[2][HH];
    __shared__ float red[2][8][4][64];

    float Wf[64], Wn[64];
    {
        const float* pf = &Whh[(size_t)(s * 64 + l) * HH + w * 64];
        const float* pn = &Whh[(size_t)(512 + s * 64 + l) * HH + w * 64];
        #pragma unroll
        for (int q = 0; q < 16; ++q) {
            float4 a = *(const float4*)&pf[q * 4];
            Wf[q*4+0] = a.x; Wf[q*4+1] = a.y; Wf[q*4+2] = a.z; Wf[q*4+3] = a.w;
            float4 b = *(const float4*)&pn[q * 4];
            Wn[q*4+0] = b.x; Wn[q*4+1] = b.y; Wn[q*4+2] = b.z; Wn[q*4+3] = b.w;
        }
    }
    asm volatile("" : P8(Wf,0),  P8(Wf,8),  P8(Wf,16), P8(Wf,24));
    asm volatile("" : P8(Wf,32), P8(Wf,40), P8(Wf,48), P8(Wf,56));
    asm volatile("" : P8(Wn,0),  P8(Wn,8),  P8(Wn,16), P8(Wn,24));
    asm volatile("" : P8(Wn,32), P8(Wn,40), P8(Wn,48), P8(Wn,56));

    const bool epi = (w < 2);
    float bfv = 0.f, bnv = 0.f, hprev = 0.f, in_cur = 0.f, in_nxt = 0.f;
    size_t obase = 0;
    if (epi) {
        bfv = bhh[s * 64 + l];
        bnv = bhh[512 + s * 64 + l];
        obase = (size_t)(c0 + w) * HH + s * 64 + l;
        in_nxt = io[obase];
    }

    const int kb = w * 64;

    for (int t = 0; t < TT; ++t) {
        const int p = t & 1;
        in_cur = in_nxt;
        if (epi && t + 1 < TT)
            in_nxt = io[obase + (size_t)(t + 1) * BB * HH];

        float v0, v1;
        if (t > 0) {
            const int tr      = t - 1;
            const int slot_r  = tr & 3;
            const unsigned ep = (unsigned)(((tr >> 2) % 3) + 1);
            const float* b0 = &hbuf[(size_t)slot_r * BB * HH
                                    + (size_t)c0 * HH + kb + l];
            const float* b1 = b0 + HH;
            for (;;) {
                v0 = __hip_atomic_load(b0, __ATOMIC_RELAXED, __HIP_MEMORY_SCOPE_AGENT);
                v1 = __hip_atomic_load(b1, __ATOMIC_RELAXED, __HIP_MEMORY_SCOPE_AGENT);
                bool ok = ((__float_as_uint(v0) & 3u) == ep) &&
                          ((__float_as_uint(v1) & 3u) == ep);
                if (__all(ok)) break;
            }
        } else {
            v0 = 0.f; v1 = 0.f;
        }
        hst[0][kb + l] = v0;
        hst[1][kb + l] = v1;

        float pf0 = 0.f, pf1 = 0.f, pn0 = 0.f, pn1 = 0.f;
        {
            float4 h0a = *(const float4*)&hst[0][kb];
            float4 h1a = *(const float4*)&hst[1][kb];
            #pragma unroll
            for (int q = 0; q < 16; ++q) {
                float4 h0b, h1b;
                if (q < 15) {
                    h0b = *(const float4*)&hst[0][kb + (q + 1) * 4];
                    h1b = *(const float4*)&hst[1][kb + (q + 1) * 4];
                }
                pf0 = fmaf(Wf[q*4+0], h0a.x, pf0); pn0 = fmaf(Wn[q*4+0], h0a.x, pn0);
                pf1 = fmaf(Wf[q*4+0], h1a.x, pf1); pn1 = fmaf(Wn[q*4+0], h1a.x, pn1);
                pf0 = fmaf(Wf[q*4+1], h0a.y, pf0); pn0 = fmaf(Wn[q*4+1], h0a.y, pn0);
                pf1 = fmaf(Wf[q*4+1], h1a.y, pf1); pn1 = fmaf(Wn[q*4+1], h1a.y, pn1);
                pf0 = fmaf(Wf[q*4+2], h0a.z, pf0); pn0 = fmaf(Wn[q*4+2], h0a.z, pn0);
                pf1 = fmaf(Wf[q*4+2], h1a.z, pf1); pn1 = fmaf(Wn[q*4+2], h1a.z, pn1);
                pf0 = fmaf(Wf[q*4+3], h0a.w, pf0); pn0 = fmaf(Wn[q*4+3], h0a.w, pn0);
                pf1 = fmaf(Wf[q*4+3], h1a.w, pf1); pn1 = fmaf(Wn[q*4+3], h1a.w, pn1);
                if ((q & 3) == 3) __builtin_amdgcn_sched_barrier(0);
                h0a = h0b; h1a = h1b;
            }
        }
        red[p][w][0][l] = pf0; red[p][w][1][l] = pf1;
        red[p][w][2][l] = pn0; red[p][w][3][l] = pn1;

        __syncthreads();

        if (epi) {
            float fs = 0.f, ns = 0.f;
            #pragma unroll
            for (int ww = 0; ww < 8; ++ww) {
                fs += red[p][ww][0 + w][l];
                ns += red[p][ww][2 + w][l];
            }
            float fg = __builtin_amdgcn_rcpf(1.f + __expf(-(fs + bfv)));
            float e2 = __expf(2.f * (in_cur + fg * (ns + bnv)));
            float nv = 1.f - 2.f * __builtin_amdgcn_rcpf(e2 + 1.f);
            float hn = nv + (1.f - fg) * (hprev - nv);
            hprev = hn;

            const unsigned ep = (unsigned)(((t >> 2) % 3) + 1);
            float ev = __uint_as_float((__float_as_uint(hn) & ~3u) | ep);
            float* dst = &hbuf[(size_t)(t & 3) * BB * HH
                               + (size_t)(c0 + w) * HH + s * 64 + l];
            __hip_atomic_store(dst, ev, __ATOMIC_RELAXED, __HIP_MEMORY_SCOPE_AGENT);
            io[obase + (size_t)t * BB * HH] = hn;
        }
    }
}

// ---------------------------------------------------------------------------
// ABLATION kernels (scratch output only; r9 skeleton).
//  MODE 2 "noLDS":  identical poll/stage/sync/epilogue, but the FMA loop
//                   reads registers instead of LDS -> isolates the cost of
//                   the 256 broadcast ds_read_b128/CU/step.
//  MODE 3 "readlane": candidate fix -- h kept per-lane in VGPRs, broadcast
//                   via v_readlane -> SGPR-operand FMA; ZERO LDS in the hot
//                   loop (384 VALU/wave vs 256 VALU + 32 LDS). Computes
//                   correct math; measured end-to-end on scratch.
// Both publish epoch-valid h so polls terminate; io writes go to a small
// ring (t&1) in d_ws; i_n loads replay the real pattern from io.
// ---------------------------------------------------------------------------
template<int MODE>
__global__ __launch_bounds__(512, 2) void mgu_abl(
    const float* __restrict__ Whh, const float* __restrict__ bhh,
    const float* __restrict__ io_rd, float* __restrict__ io_wr,
    float* __restrict__ hbuf, int steps)
{
    const int bid = blockIdx.x;
    const int s   = bid >> 5;
    const int g   = bid & 31;
    const int c0  = g * 2;
    const int tid = threadIdx.x;
    const int w   = tid >> 6;
    const int l   = tid & 63;

    __shared__ float hst[2][HH];
    __shared__ float red[2][8][4][64];

    float Wf[64], Wn[64];
    {
        const float* pf = &Whh[(size_t)(s * 64 + l) * HH + w * 64];
        const float* pn = &Whh[(size_t)(512 + s * 64 + l) * HH + w * 64];
        #pragma unroll
        for (int q = 0; q < 16; ++q) {
            float4 a = *(const float4*)&pf[q * 4];
            Wf[q*4+0] = a.x; Wf[q*4+1] = a.y; Wf[q*4+2] = a.z; Wf[q*4+3] = a.w;
            float4 b = *(const float4*)&pn[q * 4];
            Wn[q*4+0] = b.x; Wn[q*4+1] = b.y; Wn[q*4+2] = b.z; Wn[q*4+3] = b.w;
        }
    }
    asm volatile("" : P8(Wf,0),  P8(Wf,8),  P8(Wf,16), P8(Wf,24));
    asm volatile("" : P8(Wf,32), P8(Wf,40), P8(Wf,48), P8(Wf,56));
    asm volatile("" : P8(Wn,0),  P8(Wn,8),  P8(Wn,16), P8(Wn,24));
    asm volatile("" : P8(Wn,32), P8(Wn,40), P8(Wn,48), P8(Wn,56));

    const bool epi = (w < 2);
    float bfv = 0.f, bnv = 0.f, hprev = 0.f, in_cur = 0.f, in_nxt = 0.f;
    size_t obase = 0;
    if (epi) {
        bfv = bhh[s * 64 + l];
        bnv = bhh[512 + s * 64 + l];
        obase = (size_t)(c0 + w) * HH + s * 64 + l;
        in_nxt = io_rd[obase];
    }

    const int kb = w * 64;

    for (int t = 0; t < steps; ++t) {
        const int p = t & 1;
        in_cur = in_nxt;
        if (epi)
            in_nxt = io_rd[obase + (size_t)((t + 1) & 1023) * BB * HH];

        // ---- poll (identical in both modes) ----
        float v0, v1;
        if (t > 0) {
            const int tr      = t - 1;
            const int slot_r  = tr & 3;
            const unsigned ep = (unsigned)(((tr >> 2) % 3) + 1);
            const float* b0 = &hbuf[(size_t)slot_r * BB * HH
                                    + (size_t)c0 * HH + kb + l];
            const float* b1 = b0 + HH;
            for (;;) {
                v0 = __hip_atomic_load(b0, __ATOMIC_RELAXED, __HIP_MEMORY_SCOPE_AGENT);
                v1 = __hip_atomic_load(b1, __ATOMIC_RELAXED, __HIP_MEMORY_SCOPE_AGENT);
                bool ok = ((__float_as_uint(v0) & 3u) == ep) &&
                          ((__float_as_uint(v1) & 3u) == ep);
                if (__all(ok)) break;
            }
        } else {
            v0 = 0.f; v1 = 0.f;
        }

        float pf0 = 0.f, pf1 = 0.f, pn0 = 0.f, pn1 = 0.f;

        if constexpr (MODE == 2) {
            // stage (kept: part of the real structure)
            hst[0][kb + l] = v0;
            hst[1][kb + l] = v1;
            // FMA with register-sourced "h" -- no LDS reads in the hot loop
            float4 h0a = make_float4(Wf[0], Wf[1], Wf[2], Wf[3]);
            float4 h1a = make_float4(Wn[0], Wn[1], Wn[2], Wn[3]);
            #pragma unroll
            for (int q = 0; q < 16; ++q) {
                pf0 = fmaf(Wf[q*4+0], h0a.x, pf0); pn0 = fmaf(Wn[q*4+0], h0a.x, pn0);
                pf1 = fmaf(Wf[q*4+0], h1a.x, pf1); pn1 = fmaf(Wn[q*4+0], h1a.x, pn1);
                pf0 = fmaf(Wf[q*4+1], h0a.y, pf0); pn0 = fmaf(Wn[q*4+1], h0a.y, pn0);
                pf1 = fmaf(Wf[q*4+1], h1a.y, pf1); pn1 = fmaf(Wn[q*4+1], h1a.y, pn1);
                pf0 = fmaf(Wf[q*4+2], h0a.z, pf0); pn0 = fmaf(Wn[q*4+2], h0a.z, pn0);
                pf1 = fmaf(Wf[q*4+2], h1a.z, pf1); pn1 = fmaf(Wn[q*4+2], h1a.z, pn1);
                pf0 = fmaf(Wf[q*4+3], h0a.w, pf0); pn0 = fmaf(Wn[q*4+3], h0a.w, pn0);
                pf1 = fmaf(Wf[q*4+3], h1a.w, pf1); pn1 = fmaf(Wn[q*4+3], h1a.w, pn1);
                if ((q & 3) == 3) __builtin_amdgcn_sched_barrier(0);
            }
        } else {
            // MODE 3: no LDS at all -- v_readlane broadcast, SGPR-operand FMA
            #pragma unroll
            for (int k = 0; k < 64; ++k) {
                float hs0 = __int_as_float(
                    __builtin_amdgcn_readlane(__float_as_int(v0), k));
                float hs1 = __int_as_float(
                    __builtin_amdgcn_readlane(__float_as_int(v1), k));
                pf0 = fmaf(Wf[k], hs0, pf0);
                pf1 = fmaf(Wf[k], hs1, pf1);
                pn0 = fmaf(Wn[k], hs0, pn0);
                pn1 = fmaf(Wn[k], hs1, pn1);
            }
        }

        red[p][w][0][l] = pf0; red[p][w][1][l] = pf1;
        red[p][w][2][l] = pn0; red[p][w][3][l] = pn1;

        __syncthreads();

        if (epi) {
            float fs = 0.f, ns = 0.f;
            #pragma unroll
            for (int ww = 0; ww < 8; ++ww) {
                fs += red[p][ww][0 + w][l];
                ns += red[p][ww][2 + w][l];
            }
            float fg = __builtin_amdgcn_rcpf(1.f + __expf(-(fs + bfv)));
            float e2 = __expf(2.f * (in_cur + fg * (ns + bnv)));
            float nv = 1.f - 2.f * __builtin_amdgcn_rcpf(e2 + 1.f);
            float hn = nv + (1.f - fg) * (hprev - nv);
            hprev = hn;

            const unsigned ep = (unsigned)(((t >> 2) % 3) + 1);
            float ev = __uint_as_float((__float_as_uint(hn) & ~3u) | ep);
            float* dst = &hbuf[(size_t)(t & 3) * BB * HH
                               + (size_t)(c0 + w) * HH + s * 64 + l];
            __hip_atomic_store(dst, ev, __ATOMIC_RELAXED, __HIP_MEMORY_SCOPE_AGENT);
            io_wr[(size_t)(t & 1) * BB * HH + obase] = hn;
        }
    }
}

// ---------------------------------------------------------------------------
extern "C" void kernel_launch(void* const* d_in, const int* in_sizes, int n_in,
                              void* d_out, int out_size, void* d_ws, size_t ws_size,
                              hipStream_t stream)
{
    const float* x   = (const float*)d_in[0];
    const float* Wih = (const float*)d_in[1];
    const float* Whh = (const float*)d_in[2];
    const float* bih = (const float*)d_in[3];
    const float* bhh = (const float*)d_in[4];
    float* io = (float*)d_out;

    char* base = (char*)d_ws;
    const size_t S = 512 * 1024;               // one hbuf slot ring
    const size_t need = 3 * S + 256 * 1024;    // real + 2 ablation rings + io ring
    const bool abl = (ws_size >= need);

    float* hbuf = (float*)base;                // real kernel's ring

    hipMemsetAsync(d_ws, 0, abl ? need : S, stream);

    in_gemm<<<dim3(16384), dim3(256), 0, stream>>>(x, Wih, bih, io);
    mgu_rec<<<dim3(256), dim3(512), 0, stream>>>(Whh, bhh, io, hbuf);

    if (abl) {
        float* hb2 = (float*)(base + S);
        float* hb3 = (float*)(base + 2 * S);
        float* ior = (float*)(base + 3 * S);
        // noLDS at 2x steps -> tops the dispatch table (direct readout)
        mgu_abl<2><<<dim3(256), dim3(512), 0, stream>>>(Whh, bhh, io, ior, hb2, 2048);
        // readlane candidate at 1x -> inferred from total
        mgu_abl<3><<<dim3(256), dim3(512), 0, stream>>>(Whh, bhh, io, ior, hb3, 1024);
    }
}

// Round 13
// 1964.339 us; speedup vs baseline: 3.3087x; 3.3087x over previous
//
#include <hip/hip_runtime.h>

#define TT 1024
#define BB 64
#define FF 256
#define HH 512

typedef float f32x2 __attribute__((ext_vector_type(2)));
typedef float f32x4 __attribute__((ext_vector_type(4)));

// ---------------------------------------------------------------------------
// Kernel 1: i_n = x @ W_ih^T + b_ih  -> io (= d_out).  (unchanged)
// ---------------------------------------------------------------------------
__global__ __launch_bounds__(256) void in_gemm(
    const float* __restrict__ x, const float* __restrict__ Wih,
    const float* __restrict__ bih, float* __restrict__ io)
{
    __shared__ float xs[32][68];
    __shared__ float wst[64][68];

    const int bid = blockIdx.x;
    const int rb = bid >> 3, cb = bid & 7;
    const int m0 = rb * 32, n0 = cb * 64;
    const int t  = threadIdx.x;
    const int ti = t >> 4, tj = t & 15;

    float acc[2][4] = {{0.f,0.f,0.f,0.f},{0.f,0.f,0.f,0.f}};

    for (int k0 = 0; k0 < FF; k0 += 64) {
        {
            int flat = t * 8;
            int row = flat >> 6, col = flat & 63;
            const float* src = &x[(size_t)(m0 + row) * FF + k0 + col];
            float4 a = *(const float4*)&src[0];
            float4 b = *(const float4*)&src[4];
            *(float4*)&xs[row][col]     = a;
            *(float4*)&xs[row][col + 4] = b;
        }
        {
            int j  = t >> 2;
            int kk = (t & 3) * 16;
            const float* src = &Wih[(size_t)(n0 + j) * FF + k0 + kk];
            #pragma unroll
            for (int q = 0; q < 4; ++q) {
                float4 v = *(const float4*)&src[q * 4];
                wst[kk + q*4 + 0][j] = v.x;
                wst[kk + q*4 + 1][j] = v.y;
                wst[kk + q*4 + 2][j] = v.z;
                wst[kk + q*4 + 3][j] = v.w;
            }
        }
        __syncthreads();
        #pragma unroll
        for (int k = 0; k < 64; k += 4) {
            float4 xa = *(const float4*)&xs[ti][k];
            float4 xb = *(const float4*)&xs[ti + 16][k];
            #pragma unroll
            for (int q = 0; q < 4; ++q) {
                float4 wv = *(const float4*)&wst[k + q][tj * 4];
                float xav = (&xa.x)[q], xbv = (&xb.x)[q];
                acc[0][0] = fmaf(xav, wv.x, acc[0][0]);
                acc[0][1] = fmaf(xav, wv.y, acc[0][1]);
                acc[0][2] = fmaf(xav, wv.z, acc[0][2]);
                acc[0][3] = fmaf(xav, wv.w, acc[0][3]);
                acc[1][0] = fmaf(xbv, wv.x, acc[1][0]);
                acc[1][1] = fmaf(xbv, wv.y, acc[1][1]);
                acc[1][2] = fmaf(xbv, wv.z, acc[1][2]);
                acc[1][3] = fmaf(xbv, wv.w, acc[1][3]);
            }
        }
        __syncthreads();
    }

    float4 bv = *(const float4*)&bih[n0 + tj * 4];
    float4 r0 = make_float4(acc[0][0]+bv.x, acc[0][1]+bv.y, acc[0][2]+bv.z, acc[0][3]+bv.w);
    float4 r1 = make_float4(acc[1][0]+bv.x, acc[1][1]+bv.y, acc[1][2]+bv.z, acc[1][3]+bv.w);
    *(float4*)&io[(size_t)(m0 + ti)      * HH + n0 + tj * 4] = r0;
    *(float4*)&io[(size_t)(m0 + ti + 16) * HH + n0 + tj * 4] = r1;
}

// ---------------------------------------------------------------------------
// Kernel 2: ROUND-13 = round-12 design with the compile fix (ext_vector_type
// instead of HIP_vector_type float2 -- __builtin_elementwise_fma needs a true
// clang vector).
//
// r11 ablation facts: noLDS-FMA variant = 1.01 us/step (vs real 1.85) ->
// the 256 uniform-address ds_read_b128/CU/step (~2000 cy LDS pipe) were
// serializing against the ~1024 cy FMA wall. readlane broadcast: killed.
//
//  A. PACKED fp32: f32x2 + __builtin_elementwise_fma -> v_pk_fma_f32
//     (full-rate on CDNA): 256 -> 128 FMA instrs/thread, VALU issue halves.
//  B. Pipeline depth 8: sched_barrier(0) every 8 chunks -> scheduler can
//     burst ~16 ds_reads and drain them under the following FMA block.
//     Peak live: 128 W + 64 h + accs ~ 230 < 256 VGPR cap.
// Everything else (epoch-in-mantissa poll, 1 barrier/step, 2-wave epilogue,
// __expf gates, i_n prefetch) identical to r9.
// ---------------------------------------------------------------------------
#define PF2(A,i) "+v"(A[(i)+0]), "+v"(A[(i)+1]), "+v"(A[(i)+2]), "+v"(A[(i)+3]), \
                 "+v"(A[(i)+4]), "+v"(A[(i)+5]), "+v"(A[(i)+6]), "+v"(A[(i)+7])

__global__ __launch_bounds__(512, 2) void mgu_rec(
    const float* __restrict__ Whh, const float* __restrict__ bhh,
    float* __restrict__ io, float* __restrict__ hbuf)
{
    const int bid = blockIdx.x;
    const int s   = bid >> 5;     // row slice 0..7
    const int g   = bid & 31;     // batch group 0..31
    const int c0  = g * 2;
    const int tid = threadIdx.x;
    const int w   = tid >> 6;     // wave 0..7 -> 64-wide k-slice
    const int l   = tid & 63;

    __shared__ float hst[2][HH];        // staged h (4 KB)
    __shared__ float red[2][8][4][64];  // parity-buffered partials (16 KB)

    // --- persistent W as f32x2 pairs (64 aligned VGPR pairs = 128 regs) ---
    f32x2 Wf2[32], Wn2[32];
    {
        const float* pf = &Whh[(size_t)(s * 64 + l) * HH + w * 64];
        const float* pn = &Whh[(size_t)(512 + s * 64 + l) * HH + w * 64];
        #pragma unroll
        for (int q = 0; q < 32; ++q) {
            Wf2[q] = *(const f32x2*)&pf[q * 2];
            Wn2[q] = *(const f32x2*)&pn[q * 2];
        }
    }
    // pins: constant indices only; f32x2 "v" operands = aligned reg pairs
    asm volatile("" : PF2(Wf2,0),  PF2(Wf2,8));
    asm volatile("" : PF2(Wf2,16), PF2(Wf2,24));
    asm volatile("" : PF2(Wn2,0),  PF2(Wn2,8));
    asm volatile("" : PF2(Wn2,16), PF2(Wn2,24));

    const bool epi = (w < 2);
    float bfv = 0.f, bnv = 0.f, hprev = 0.f, in_cur = 0.f, in_nxt = 0.f;
    size_t obase = 0;
    if (epi) {
        bfv = bhh[s * 64 + l];
        bnv = bhh[512 + s * 64 + l];
        obase = (size_t)(c0 + w) * HH + s * 64 + l;
        in_nxt = io[obase];
    }

    const int kb = w * 64;

    for (int t = 0; t < TT; ++t) {
        const int p = t & 1;
        in_cur = in_nxt;
        if (epi && t + 1 < TT)
            in_nxt = io[obase + (size_t)(t + 1) * BB * HH];

        // ---- epoch-in-mantissa data poll (detection == data arrival) ----
        float v0, v1;
        if (t > 0) {
            const int tr      = t - 1;
            const int slot_r  = tr & 3;
            const unsigned ep = (unsigned)(((tr >> 2) % 3) + 1);
            const float* b0 = &hbuf[(size_t)slot_r * BB * HH
                                    + (size_t)c0 * HH + kb + l];
            const float* b1 = b0 + HH;
            for (;;) {
                v0 = __hip_atomic_load(b0, __ATOMIC_RELAXED, __HIP_MEMORY_SCOPE_AGENT);
                v1 = __hip_atomic_load(b1, __ATOMIC_RELAXED, __HIP_MEMORY_SCOPE_AGENT);
                bool ok = ((__float_as_uint(v0) & 3u) == ep) &&
                          ((__float_as_uint(v1) & 3u) == ep);
                if (__all(ok)) break;
            }
        } else {
            v0 = 0.f; v1 = 0.f;
        }
        hst[0][kb + l] = v0;   // wave-private slice
        hst[1][kb + l] = v1;

        // ---- packed, depth-8-pipelined dot products ----
        f32x2 af0 = (f32x2)(0.f), af1 = (f32x2)(0.f);
        f32x2 an0 = (f32x2)(0.f), an1 = (f32x2)(0.f);
        #pragma unroll
        for (int q = 0; q < 16; ++q) {
            f32x4 h0 = *(const f32x4*)&hst[0][kb + q * 4];
            f32x4 h1 = *(const f32x4*)&hst[1][kb + q * 4];
            f32x2 h0lo = h0.xy, h0hi = h0.zw;
            f32x2 h1lo = h1.xy, h1hi = h1.zw;
            af0 = __builtin_elementwise_fma(Wf2[2*q+0], h0lo, af0);
            an0 = __builtin_elementwise_fma(Wn2[2*q+0], h0lo, an0);
            af1 = __builtin_elementwise_fma(Wf2[2*q+0], h1lo, af1);
            an1 = __builtin_elementwise_fma(Wn2[2*q+0], h1lo, an1);
            af0 = __builtin_elementwise_fma(Wf2[2*q+1], h0hi, af0);
            an0 = __builtin_elementwise_fma(Wn2[2*q+1], h0hi, an0);
            af1 = __builtin_elementwise_fma(Wf2[2*q+1], h1hi, af1);
            an1 = __builtin_elementwise_fma(Wn2[2*q+1], h1hi, an1);
            if ((q & 7) == 7) __builtin_amdgcn_sched_barrier(0);
        }
        red[p][w][0][l] = af0.x + af0.y;
        red[p][w][1][l] = af1.x + af1.y;
        red[p][w][2][l] = an0.x + an0.y;
        red[p][w][3][l] = an1.x + an1.y;

        __syncthreads();   // the only intra-WG barrier per step

        // ---- epilogue: wave 0 -> batch 0, wave 1 -> batch 1 ----
        if (epi) {
            float fs = 0.f, ns = 0.f;
            #pragma unroll
            for (int ww = 0; ww < 8; ++ww) {
                fs += red[p][ww][0 + w][l];
                ns += red[p][ww][2 + w][l];
            }
            float fg = __builtin_amdgcn_rcpf(1.f + __expf(-(fs + bfv)));
            float e2 = __expf(2.f * (in_cur + fg * (ns + bnv)));
            float nv = 1.f - 2.f * __builtin_amdgcn_rcpf(e2 + 1.f);
            float hn = nv + (1.f - fg) * (hprev - nv);
            hprev = hn;

            // publish epoch-encoded h FIRST (critical path), io after
            const unsigned ep = (unsigned)(((t >> 2) % 3) + 1);
            float ev = __uint_as_float((__float_as_uint(hn) & ~3u) | ep);
            float* dst = &hbuf[(size_t)(t & 3) * BB * HH
                               + (size_t)(c0 + w) * HH + s * 64 + l];
            __hip_atomic_store(dst, ev, __ATOMIC_RELAXED, __HIP_MEMORY_SCOPE_AGENT);
            io[obase + (size_t)t * BB * HH] = hn;
        }
        // no trailing barrier: hst wave-private, red parity-buffered
    }
}

// ---------------------------------------------------------------------------
extern "C" void kernel_launch(void* const* d_in, const int* in_sizes, int n_in,
                              void* d_out, int out_size, void* d_ws, size_t ws_size,
                              hipStream_t stream)
{
    const float* x   = (const float*)d_in[0];
    const float* Wih = (const float*)d_in[1];
    const float* Whh = (const float*)d_in[2];
    const float* bih = (const float*)d_in[3];
    const float* bhh = (const float*)d_in[4];
    float* io = (float*)d_out;

    float* hbuf = (float*)d_ws;   // 4 slots x 64 batches x 512 f32 = 512 KB

    // zero the slot ring: epoch bits 0 never match live epochs {1,2,3};
    // re-runs every launch/replay -> deterministic.
    (void)hipMemsetAsync(d_ws, 0, 4 * BB * HH * 4, stream);

    in_gemm<<<dim3(16384), dim3(256), 0, stream>>>(x, Wih, bih, io);
    mgu_rec<<<dim3(256), dim3(512), 0, stream>>>(Whh, bhh, io, hbuf);
}